// Round 9
// baseline (252.790 us; speedup 1.0000x reference)
//
#include <hip/hip_runtime.h>
#include <hip/hip_fp16.h>

#define NN 50000     // nodes
#define NE 800000    // edges
#define NG 1024      // graphs
#define NP 16384     // pairs
#define NCL 16       // cell lines
#define INCH 64
#define EMB 128
#define HID 256

#define NB 391       // node buckets of 128 (CDIV(NN,128))
#define NCHUNK 400   // edge chunks
#define EPB 2000     // edges per chunk (NE = 400*2000 exactly)

#define CDIV(a,b) (((a)+(b)-1)/(b))

// ---------------- block exclusive scan (NW waves) ----------------
template<int NW>
__device__ __forceinline__ int block_excl_scan(int v, int t, int* incl_out) {
    int lane = t & 63, w = t >> 6;
    int s = v;
#pragma unroll
    for (int d = 1; d < 64; d <<= 1) {
        int u = __shfl_up(s, d, 64);
        if (lane >= d) s += u;
    }
    __shared__ int wsum[NW];
    if (lane == 63) wsum[w] = s;
    __syncthreads();
    int add = 0;
    for (int k = 0; k < w; ++k) add += wsum[k];
    *incl_out = s + add;
    return s + add - v;
}

// ---------------- Pass A: per-chunk bucket histogram ----------------
__global__ __launch_bounds__(256) void k_cnt(const int* __restrict__ cols,
                                             int* __restrict__ cnt) {
    __shared__ int hist[NB];
    int ch = blockIdx.x, t = threadIdx.x;
    for (int b = t; b < NB; b += 256) hist[b] = 0;
    __syncthreads();
    for (int e = ch * EPB + t; e < (ch + 1) * EPB; e += 256)
        atomicAdd(&hist[cols[e] >> 7], 1);
    __syncthreads();
    for (int b = t; b < NB; b += 256) cnt[b * NCHUNK + ch] = hist[b];
}

// ---------------- Pass B1: per-bucket scan over chunks ----------------
__global__ __launch_bounds__(512) void k_bscan(int* __restrict__ cnt,
                                               int* __restrict__ btot) {
    int b = blockIdx.x, t = threadIdx.x;
    int v = (t < NCHUNK) ? cnt[b * NCHUNK + t] : 0;
    int incl;
    int excl = block_excl_scan<8>(v, t, &incl);
    if (t < NCHUNK) cnt[b * NCHUNK + t] = excl;
    if (t == NCHUNK - 1) btot[b] = incl;
}

// ---------------- Pass B2: bucket-base scan ----------------
__global__ __launch_bounds__(512) void k_btot(const int* __restrict__ btot,
                                              int* __restrict__ bbase) {
    int t = threadIdx.x;
    int v = (t < NB) ? btot[t] : 0;
    int incl;
    int excl = block_excl_scan<8>(v, t, &incl);
    if (t < NB) bbase[t] = excl;
    if (t == NB - 1) bbase[NB] = incl;   // = NE
}

// ---------------- Pass C: partition edges into bucket-grouped ebuf ----------------
__global__ __launch_bounds__(256) void k_part(const int* __restrict__ rows,
                                              const int* __restrict__ cols,
                                              const int* __restrict__ cnt,
                                              const int* __restrict__ bbase,
                                              int2* __restrict__ ebuf) {
    __shared__ int cur[NB];
    int ch = blockIdx.x, t = threadIdx.x;
    for (int b = t; b < NB; b += 256) cur[b] = bbase[b] + cnt[b * NCHUNK + ch];
    __syncthreads();
    for (int e = ch * EPB + t; e < (ch + 1) * EPB; e += 256) {
        int c = cols[e], r = rows[e];
        int pos = atomicAdd(&cur[c >> 7], 1);
        ebuf[pos] = make_int2(r, c);
    }
}

// ---------------- Pass D: per-bucket counting sort -> srows/off/dinv + x->fp16 sliced ----------------
// xs layout: slice-blocked [2][NN][32 halfs] (slice = 32 feats = 64B line)
__global__ __launch_bounds__(256) void k_bsort(const int2* __restrict__ ebuf,
                                               const int* __restrict__ bbase,
                                               const float* __restrict__ x,
                                               int* __restrict__ off,
                                               float* __restrict__ dinv,
                                               int* __restrict__ srows,
                                               __half* __restrict__ xs) {
    __shared__ int   ldeg[128];
    __shared__ int   lcur[128];
    __shared__ float ldinv[128];
    int b = blockIdx.x, t = threadIdx.x;
    int n0 = b << 7;
    int nloc = min(128, NN - n0);
    int beg = bbase[b], end = bbase[b + 1];
    if (t < 128) ldeg[t] = 0;
    __syncthreads();
    for (int i = beg + t; i < end; i += 256)
        atomicAdd(&ldeg[ebuf[i].y - n0], 1);
    __syncthreads();
    int v = (t < nloc) ? ldeg[t] : 0;
    int incl;
    int excl = block_excl_scan<4>(v, t, &incl);
    if (t < nloc) {
        off[n0 + t]  = beg + excl + v;            // END offset convention
        float d = rsqrtf((float)(v + 1));         // +1 self-loop
        dinv[n0 + t] = d;
        ldinv[t] = d;
        lcur[t] = beg + excl;
    }
    __syncthreads();
    for (int i = beg + t; i < end; i += 256) {
        int2 e = ebuf[i];
        int pos = atomicAdd(&lcur[e.y - n0], 1);
        srows[pos] = e.x;
    }
    // fused: xs[slice][row][...] = fp16(dinv[row] * x[row]) for this bucket
    const float4* Xx = (const float4*)x;
#pragma unroll
    for (int i = 0; i < 8; ++i) {
        int f4 = t + i * 256;                     // 0..2047 (128 rows x 16 f4)
        int rloc = f4 >> 4, kq = f4 & 15;
        if (rloc < nloc) {
            float d = ldinv[rloc];
            float4 vv = Xx[(size_t)(n0 + rloc) * 16 + kq];
            __half2 h[2];
            h[0] = __floats2half2_rn(d * vv.x, d * vv.y);
            h[1] = __floats2half2_rn(d * vv.z, d * vv.w);
            int sl = kq >> 3;                     // feature slice (32 feats)
            ((float2*)xs)[(size_t)sl * NN * 8 + (size_t)(n0 + rloc) * 8 + (kq & 7)]
                = *(float2*)h;
        }
    }
}

// ---------------- XCD-affine sliced gather (64B line per slice-row) ----------------
// SRC slice-blocked fp16 [NSL][NN][32], pre-scaled by dinv[row].
// DST row-major f32 [NN][FEAT]: DST[c] = dinv[c]*(sum_e SRC'[r] + SRC'[c]).
// Block b -> slice b%NSL (round-robin XCD dispatch pins slice to XCD set).
// Wave = 1 node's slice: 16 edge slots x 4 feature lanes (float4 = 8 halfs).
template<int FEAT, int NSL>
__global__ __launch_bounds__(256) void k_gath_s(const int* __restrict__ off,
                                                const int* __restrict__ srows,
                                                const float* __restrict__ dinv,
                                                const __half* __restrict__ SRC,
                                                float* __restrict__ DST) {
    int b = blockIdx.x;
    int s = b % NSL;
    int node = (b / NSL) * 4 + (threadIdx.x >> 6);
    int lane = threadIdx.x & 63;
    int slot = lane >> 2, q = lane & 3;
    int beg = node ? off[node - 1] : 0;
    int end = off[node];
    float di = dinv[node];
    const float4* S4 = (const float4*)(SRC + (size_t)s * NN * 32);  // 4 f4/row

    float acc[8];
#pragma unroll
    for (int j = 0; j < 8; ++j) acc[j] = 0.f;

    if (slot == 0) {   // self-loop
        float4 raw = S4[node * 4 + q];
        const __half2* h = (const __half2*)&raw;
#pragma unroll
        for (int j = 0; j < 4; ++j) {
            float2 f = __half22float2(h[j]);
            acc[2 * j + 0] = f.x;
            acc[2 * j + 1] = f.y;
        }
    }
    for (int e = beg + slot; e < end; e += 16) {
        int r = srows[e];
        float4 raw = S4[r * 4 + q];
        const __half2* h = (const __half2*)&raw;
#pragma unroll
        for (int j = 0; j < 4; ++j) {
            float2 f = __half22float2(h[j]);
            acc[2 * j + 0] += f.x;
            acc[2 * j + 1] += f.y;
        }
    }
    // reduce over the 16 edge slots (xor lane bits 2..5)
#pragma unroll
    for (int d = 4; d < 64; d <<= 1)
#pragma unroll
        for (int j = 0; j < 8; ++j)
            acc[j] += __shfl_xor(acc[j], d, 64);

    if (slot == 0) {
        float4* D4 = (float4*)DST;
        size_t base = ((size_t)node * FEAT + s * 32 + q * 8) >> 2;
        D4[base + 0] = make_float4(di * acc[0], di * acc[1], di * acc[2], di * acc[3]);
        D4[base + 1] = make_float4(di * acc[4], di * acc[5], di * acc[6], di * acc[7]);
    }
}

// ---------------- GEMM: Y[M,128] = X[M,K] @ W[K,128] (+bias,relu[,rowscale][,sliced fp16 out]) ----------------
template<int K, bool EPI, bool RS, bool HOUT>
__global__ __launch_bounds__(256) void gemm32(const float* __restrict__ X,
                                              const float* __restrict__ W,
                                              const float* __restrict__ bias,
                                              const float* __restrict__ rs,
                                              float* __restrict__ Y, int M) {
    __shared__ float Xt[32][36];
    __shared__ float Wsh[32][128];
    const int t  = threadIdx.x;
    const int tr = t >> 5;
    const int tc = t & 31;
    const int row0 = blockIdx.x * 32;
    const int rr = t >> 3, kq = t & 7;

    float acc[4][4];
#pragma unroll
    for (int i = 0; i < 4; ++i)
#pragma unroll
        for (int j = 0; j < 4; ++j) acc[i][j] = 0.f;

    const float4* X4 = (const float4*)X;
    const float4* W4 = (const float4*)W;
    float4* Ws4 = (float4*)&Wsh[0][0];

    for (int k0 = 0; k0 < K; k0 += 32) {
        __syncthreads();
        int gr = row0 + rr;
        float4 xv = (gr < M) ? X4[gr * (K >> 2) + (k0 >> 2) + kq]
                             : make_float4(0.f, 0.f, 0.f, 0.f);
        Xt[4 * kq + 0][rr] = xv.x;
        Xt[4 * kq + 1][rr] = xv.y;
        Xt[4 * kq + 2][rr] = xv.z;
        Xt[4 * kq + 3][rr] = xv.w;
#pragma unroll
        for (int i = t; i < 32 * 32; i += 256)
            Ws4[i] = W4[(k0 + (i >> 5)) * 32 + (i & 31)];
        __syncthreads();
#pragma unroll 4
        for (int k = 0; k < 32; ++k) {
            float4 xf = *reinterpret_cast<const float4*>(&Xt[k][4 * tr]);
            float4 wf = *reinterpret_cast<const float4*>(&Wsh[k][4 * tc]);
            float xs[4] = {xf.x, xf.y, xf.z, xf.w};
            float ws[4] = {wf.x, wf.y, wf.z, wf.w};
#pragma unroll
            for (int i = 0; i < 4; ++i)
#pragma unroll
                for (int j = 0; j < 4; ++j)
                    acc[i][j] = fmaf(xs[i], ws[j], acc[i][j]);
        }
    }
    float4 b = make_float4(0.f, 0.f, 0.f, 0.f);
    if (EPI) b = ((const float4*)bias)[tc];
    float4* Y4 = (float4*)Y;
    __half*  Yh = (__half*)Y;
#pragma unroll
    for (int i = 0; i < 4; ++i) {
        int gr = row0 + 4 * tr + i;
        if (gr < M) {
            float4 o = make_float4(acc[i][0] + b.x, acc[i][1] + b.y,
                                   acc[i][2] + b.z, acc[i][3] + b.w);
            if (EPI) {
                o.x = o.x > 0.f ? o.x : 0.f;
                o.y = o.y > 0.f ? o.y : 0.f;
                o.z = o.z > 0.f ? o.z : 0.f;
                o.w = o.w > 0.f ? o.w : 0.f;
            }
            if (RS) {
                float d = rs[gr];
                o.x *= d; o.y *= d; o.z *= d; o.w *= d;
            }
            if (HOUT) {
                // slice-blocked fp16 [4][M][32]: slice = tc/8, offset (4tc)%32
                __half2 h[2];
                h[0] = __floats2half2_rn(o.x, o.y);
                h[1] = __floats2half2_rn(o.z, o.w);
                ((float2*)Yh)[(size_t)(tc >> 3) * M * 8 + (size_t)gr * 8 + (tc & 7)]
                    = *(float2*)h;
            } else {
                Y4[gr * 32 + tc] = o;
            }
        }
    }
}

// ---------------- mean pool (gstart search fused) ----------------
__global__ __launch_bounds__(128) void k_pool2(const float* __restrict__ H,
                                               const int* __restrict__ batch,
                                               float* __restrict__ gsum) {
    int g = blockIdx.x;
    __shared__ int se[2];
    if (threadIdx.x < 2) {
        int tgt = g + threadIdx.x;
        int lo = 0, hi = NN;
        while (lo < hi) {
            int m = (lo + hi) >> 1;
            if (batch[m] < tgt) lo = m + 1; else hi = m;
        }
        se[threadIdx.x] = lo;
    }
    __syncthreads();
    int s = se[0], e = se[1];
    int j = threadIdx.x;
    float acc = 0.f;
    for (int i = s; i < e; ++i) acc += H[(long long)i * 128 + j];
    float c = (float)(e - s);
    gsum[g * 128 + j] = acc / fmaxf(c, 1.f);
}

// ---------------- batched GEMM: AB[z][g][t] = GE @ W1-half (128x128 tile, 8x8/thr) ----------------
__global__ __launch_bounds__(256) void gemm_bat(const float* __restrict__ GE,
                                                const float* __restrict__ W1,
                                                float* __restrict__ AB) {
    __shared__ float Xt[32][132];
    __shared__ float Wsh[32][128];
    const int t  = threadIdx.x;
    const int tr = t >> 4;
    const int tc = t & 15;
    const int row0 = blockIdx.x * 128;
    const int y = blockIdx.y;
    const int z = blockIdx.z;

    const float* Wbase = W1 + (z >> 1) * (HID * HID) + (z & 1) * (128 * HID) + y * 128;

    float acc[8][8];
#pragma unroll
    for (int i = 0; i < 8; ++i)
#pragma unroll
        for (int j = 0; j < 8; ++j) acc[i][j] = 0.f;

    const float4* X4 = (const float4*)GE;

    for (int k0 = 0; k0 < 128; k0 += 32) {
        __syncthreads();
#pragma unroll
        for (int i = 0; i < 4; ++i) {
            int f4 = t + i * 256;
            int row = f4 >> 3, kq = f4 & 7;
            float4 xv = X4[(row0 + row) * 32 + (k0 >> 2) + kq];
            Xt[4 * kq + 0][row] = xv.x;
            Xt[4 * kq + 1][row] = xv.y;
            Xt[4 * kq + 2][row] = xv.z;
            Xt[4 * kq + 3][row] = xv.w;
        }
        const float4* Wc4 = (const float4*)(Wbase + k0 * HID);
#pragma unroll
        for (int i = 0; i < 4; ++i) {
            int f4 = t + i * 256;
            int k = f4 >> 5, c4 = f4 & 31;
            ((float4*)&Wsh[k][0])[c4] = Wc4[k * 64 + c4];
        }
        __syncthreads();
#pragma unroll 2
        for (int k = 0; k < 32; ++k) {
            float xf[8], wf[8];
            *(float4*)&xf[0] = *(const float4*)&Xt[k][8 * tr];
            *(float4*)&xf[4] = *(const float4*)&Xt[k][8 * tr + 4];
            *(float4*)&wf[0] = *(const float4*)&Wsh[k][8 * tc];
            *(float4*)&wf[4] = *(const float4*)&Wsh[k][8 * tc + 4];
#pragma unroll
            for (int i = 0; i < 8; ++i)
#pragma unroll
                for (int j = 0; j < 8; ++j)
                    acc[i][j] = fmaf(xf[i], wf[j], acc[i][j]);
        }
    }
    float4* O4 = (float4*)AB;
#pragma unroll
    for (int i = 0; i < 8; ++i) {
        int g = row0 + 8 * tr + i;
        size_t base = ((size_t)(z * NG + g) * HID + y * 128 + 8 * tc) >> 2;
        O4[base + 0] = make_float4(acc[i][0], acc[i][1], acc[i][2], acc[i][3]);
        O4[base + 1] = make_float4(acc[i][4], acc[i][5], acc[i][6], acc[i][7]);
    }
}

// ---------------- pair epilogue ----------------
__global__ __launch_bounds__(256) void k_pair(const float* __restrict__ AB,
                                              const int* __restrict__ ddb,
                                              const int* __restrict__ ecl,
                                              const float* __restrict__ B1,
                                              const float* __restrict__ W2,
                                              const float* __restrict__ B2,
                                              float* __restrict__ out) {
    int p = blockIdx.x * 4 + (threadIdx.x >> 6);
    int lane = threadIdx.x & 63;
    int c = ecl[p];
    int a = ddb[p];
    int b = ddb[NP + p];
    const float4* rA = (const float4*)&AB[((c * 2 + 0) * NG + a) * HID];
    const float4* rB = (const float4*)&AB[((c * 2 + 1) * NG + b) * HID];
    const float4* b1 = (const float4*)&B1[c * HID];
    const float4* w2 = (const float4*)&W2[c * HID];
    float4 va = rA[lane], vb = rB[lane], v1 = b1[lane], v2 = w2[lane];
    float hx = va.x + vb.x + v1.x;
    float hy = va.y + vb.y + v1.y;
    float hz = va.z + vb.z + v1.z;
    float hw = va.w + vb.w + v1.w;
    float s = 0.f;
    s = fmaf(hx > 0.f ? hx : 0.f, v2.x, s);
    s = fmaf(hy > 0.f ? hy : 0.f, v2.y, s);
    s = fmaf(hz > 0.f ? hz : 0.f, v2.z, s);
    s = fmaf(hw > 0.f ? hw : 0.f, v2.w, s);
    for (int o = 32; o; o >>= 1) s += __shfl_down(s, o, 64);
    if (lane == 0) out[p] = s + B2[c];
}

// ---------------- launch ----------------
extern "C" void kernel_launch(void* const* d_in, const int* in_sizes, int n_in,
                              void* d_out, int out_size, void* d_ws, size_t ws_size,
                              hipStream_t stream) {
    const float* x    = (const float*)d_in[0];
    const float* c1w  = (const float*)d_in[1];
    const float* c1b  = (const float*)d_in[2];
    const float* c2w  = (const float*)d_in[3];
    const float* c2b  = (const float*)d_in[4];
    const float* rw1  = (const float*)d_in[5];
    const float* rb1  = (const float*)d_in[6];
    const float* rw2  = (const float*)d_in[7];
    const float* rb2  = (const float*)d_in[8];
    const int*   eidx = (const int*)d_in[9];    // [2, NE]: rows then cols
    const int*   batch= (const int*)d_in[10];
    const int*   ddb  = (const int*)d_in[11];   // [2, NP]
    const int*   ecl  = (const int*)d_in[12];
    float* out = (float*)d_out;

    // ---- workspace layout (floats) ----
    // off(50048) | srows(NE) | dinv(50048) | bufA(NN*128) | bufB(NN*128)
    // aliases:
    //   ebuf (int2, NE)       -> bufA                        (passes C..D)
    //   cnt/btot/bbase (ints) -> bufB[1.70M ..)              (passes A..D)
    //   xs  (fp16 [2][NN][32])-> bufB[0 .. 1.6M floats)      (D .. gather1)
    //   H1h (fp16 [4][NN][32])-> bufB[0 .. 3.2M floats)      (gemm1 .. gather2)
    //   H2  (f32 NN*128)      -> bufB                        (gemm2 .. pool)
    //   gsum                  -> srows region                (post pool)
    //   AB (32*NG*HID f32)    -> bufA (+spills into bufB)    (post pool)
    int*   off   = (int*)d_ws;
    int*   srows = off + 50048;
    float* dinv  = (float*)(srows + NE);
    float* bufA  = dinv + 50048;
    float* bufB  = bufA + NN * EMB;

    int2*  ebuf  = (int2*)bufA;
    int*   cnt   = (int*)(bufB + 1700000);
    int*   btot  = cnt + NB * NCHUNK;
    int*   bbase = btot + 512;
    __half* xs   = (__half*)bufB;
    __half* H1h  = (__half*)bufB;
    float* gsum  = (float*)srows;
    float* AB    = bufA;

    const int* erow = eidx;
    const int* ecol = eidx + NE;

    // ---- CSR build (bucketed, LDS-atomic only) + fused x->fp16 sliced prescale ----
    k_cnt  <<<NCHUNK, 256, 0, stream>>>(ecol, cnt);
    k_bscan<<<NB,     512, 0, stream>>>(cnt, btot);
    k_btot <<<1,      512, 0, stream>>>(btot, bbase);
    k_part <<<NCHUNK, 256, 0, stream>>>(erow, ecol, cnt, bbase, ebuf);
    k_bsort<<<NB,     256, 0, stream>>>(ebuf, bbase, x, off, dinv, srows, xs);

    // ---- layer 1: aggX = gather(xs) [2 slices] ; H1'(fp16 sliced) = dinv*relu(aggX@W1+b1) ----
    k_gath_s<INCH,2><<<2*(NN/4),256,0,stream>>>(off, srows, dinv, xs, bufA);
    gemm32<INCH,true,true,true><<<CDIV(NN,32),256,0,stream>>>(bufA, c1w, c1b, dinv, (float*)H1h, NN);

    // ---- layer 2: aggH = gather(H1') [4 slices] ; H2 = relu(aggH@W2+b2) ----
    k_gath_s<EMB,4><<<4*(NN/4),256,0,stream>>>(off, srows, dinv, H1h, bufA);
    gemm32<EMB,true,false,false><<<CDIV(NN,32),256,0,stream>>>(bufA, c2w, c2b, nullptr, bufB, NN);

    // ---- mean pool over sorted batch ----
    k_pool2<<<NG,128,0,stream>>>(bufB, batch, gsum);

    // ---- regressor: AB = GE @ W1 halves for all 16 lines, then pair epilogue ----
    dim3 bgrid(NG/128, 2, 2*NCL);
    gemm_bat<<<bgrid,256,0,stream>>>(gsum, rw1, AB);
    k_pair<<<NP/4,256,0,stream>>>(AB, ddb, ecl, rb1, rw2, rb2, out);
}

// Round 10
// 197.321 us; speedup vs baseline: 1.2811x; 1.2811x over previous
//
#include <hip/hip_runtime.h>
#include <hip/hip_fp16.h>

#define NN 50000     // nodes
#define NE 800000    // edges
#define NG 1024      // graphs
#define NP 16384     // pairs
#define NCL 16       // cell lines
#define INCH 64
#define EMB 128
#define HID 256

#define NB 391       // node buckets of 128 (CDIV(NN,128))
#define NCHUNK 400   // edge chunks
#define EPB 2000     // edges per chunk (NE = 400*2000 exactly)

#define CDIV(a,b) (((a)+(b)-1)/(b))

// ---------------- block exclusive scan (NW waves) ----------------
template<int NW>
__device__ __forceinline__ int block_excl_scan(int v, int t, int* incl_out) {
    int lane = t & 63, w = t >> 6;
    int s = v;
#pragma unroll
    for (int d = 1; d < 64; d <<= 1) {
        int u = __shfl_up(s, d, 64);
        if (lane >= d) s += u;
    }
    __shared__ int wsum[NW];
    if (lane == 63) wsum[w] = s;
    __syncthreads();
    int add = 0;
    for (int k = 0; k < w; ++k) add += wsum[k];
    *incl_out = s + add;
    return s + add - v;
}

// ---------------- Pass A: per-chunk bucket histogram ----------------
__global__ __launch_bounds__(256) void k_cnt(const int* __restrict__ cols,
                                             int* __restrict__ cnt) {
    __shared__ int hist[NB];
    int ch = blockIdx.x, t = threadIdx.x;
    for (int b = t; b < NB; b += 256) hist[b] = 0;
    __syncthreads();
    for (int e = ch * EPB + t; e < (ch + 1) * EPB; e += 256)
        atomicAdd(&hist[cols[e] >> 7], 1);
    __syncthreads();
    for (int b = t; b < NB; b += 256) cnt[b * NCHUNK + ch] = hist[b];
}

// ---------------- Pass B1: per-bucket scan over chunks ----------------
__global__ __launch_bounds__(512) void k_bscan(int* __restrict__ cnt,
                                               int* __restrict__ btot) {
    int b = blockIdx.x, t = threadIdx.x;
    int v = (t < NCHUNK) ? cnt[b * NCHUNK + t] : 0;
    int incl;
    int excl = block_excl_scan<8>(v, t, &incl);
    if (t < NCHUNK) cnt[b * NCHUNK + t] = excl;
    if (t == NCHUNK - 1) btot[b] = incl;
}

// ---------------- Pass B2: bucket-base scan ----------------
__global__ __launch_bounds__(512) void k_btot(const int* __restrict__ btot,
                                              int* __restrict__ bbase) {
    int t = threadIdx.x;
    int v = (t < NB) ? btot[t] : 0;
    int incl;
    int excl = block_excl_scan<8>(v, t, &incl);
    if (t < NB) bbase[t] = excl;
    if (t == NB - 1) bbase[NB] = incl;   // = NE
}

// ---------------- Pass C: partition edges (packed r<<7|c_local) ----------------
__global__ __launch_bounds__(256) void k_part(const int* __restrict__ rows,
                                              const int* __restrict__ cols,
                                              const int* __restrict__ cnt,
                                              const int* __restrict__ bbase,
                                              int* __restrict__ ebuf) {
    __shared__ int cur[NB];
    int ch = blockIdx.x, t = threadIdx.x;
    for (int b = t; b < NB; b += 256) cur[b] = bbase[b] + cnt[b * NCHUNK + ch];
    __syncthreads();
    for (int e = ch * EPB + t; e < (ch + 1) * EPB; e += 256) {
        int c = cols[e], r = rows[e];
        int pos = atomicAdd(&cur[c >> 7], 1);
        ebuf[pos] = (r << 7) | (c & 127);
    }
}

// ---------------- Pass D: per-bucket counting sort -> srows/off/dinv + x->fp16 ----------------
__global__ __launch_bounds__(256) void k_bsort(const int* __restrict__ ebuf,
                                               const int* __restrict__ bbase,
                                               const float* __restrict__ x,
                                               int* __restrict__ off,
                                               float* __restrict__ dinv,
                                               int* __restrict__ srows,
                                               __half* __restrict__ xs) {
    __shared__ int   ldeg[128];
    __shared__ int   lcur[128];
    __shared__ float ldinv[128];
    int b = blockIdx.x, t = threadIdx.x;
    int n0 = b << 7;
    int nloc = min(128, NN - n0);
    int beg = bbase[b], end = bbase[b + 1];
    if (t < 128) ldeg[t] = 0;
    __syncthreads();
    for (int i = beg + t; i < end; i += 256)
        atomicAdd(&ldeg[ebuf[i] & 127], 1);
    __syncthreads();
    int v = (t < nloc) ? ldeg[t] : 0;
    int incl;
    int excl = block_excl_scan<4>(v, t, &incl);
    if (t < nloc) {
        off[n0 + t]  = beg + excl + v;            // END offset convention
        float d = rsqrtf((float)(v + 1));         // +1 self-loop
        dinv[n0 + t] = d;
        ldinv[t] = d;
        lcur[t] = beg + excl;
    }
    __syncthreads();
    for (int i = beg + t; i < end; i += 256) {
        int e = ebuf[i];
        int pos = atomicAdd(&lcur[e & 127], 1);
        srows[pos] = e >> 7;
    }
    // fused: xs[row] = fp16(dinv[row] * x[row]) for this bucket's rows
    const float4* Xx = (const float4*)x;
#pragma unroll
    for (int i = 0; i < 8; ++i) {
        int f4 = t + i * 256;                     // 0..2047 (128 rows x 16 f4)
        int rloc = f4 >> 4, kq = f4 & 15;
        if (rloc < nloc) {
            float d = ldinv[rloc];
            float4 vv = Xx[(size_t)(n0 + rloc) * 16 + kq];
            __half2 h[2];
            h[0] = __floats2half2_rn(d * vv.x, d * vv.y);
            h[1] = __floats2half2_rn(d * vv.z, d * vv.w);
            ((float2*)xs)[(size_t)(n0 + rloc) * 16 + kq] = *(float2*)h;
        }
    }
}

// ---------------- gather on pre-scaled fp16 rows, fp16 output ----------------
// SRC' (fp16) already scaled by dinv[row]; DST[c] = fp16(dinv[c]*(sum_e SRC'[r] + SRC'[c])).
// ZB: first 512 blocks also zero zbuf[131072] (gsum) -- free fusion.
template<int FEAT, bool ZB>
__global__ __launch_bounds__(256) void k_gath_h(const int* __restrict__ off,
                                                const int* __restrict__ srows,
                                                const float* __restrict__ dinv,
                                                const __half* __restrict__ SRC,
                                                __half* __restrict__ DST,
                                                float* __restrict__ zbuf) {
    if (ZB) {
        if (blockIdx.x < 512) zbuf[(blockIdx.x << 8) + threadIdx.x] = 0.f;
    }
    constexpr int NC = FEAT / 8;    // 16B chunks (8 halfs) per row
    constexpr int PL = NC / 8;      // chunks per lane (1 for 64, 2 for 128)
    int node = blockIdx.x * 4 + (threadIdx.x >> 6);
    int lane = threadIdx.x & 63;
    int slot = lane >> 3, q = lane & 7;
    if (node >= NN) return;
    int beg = node ? off[node - 1] : 0;
    int end = off[node];
    float di = dinv[node];
    const float4* S4 = (const float4*)SRC;

    float acc[PL][8];
#pragma unroll
    for (int i = 0; i < PL; ++i)
#pragma unroll
        for (int j = 0; j < 8; ++j) acc[i][j] = 0.f;

    if (slot == 0) {
#pragma unroll
        for (int i = 0; i < PL; ++i) {
            float4 raw = S4[node * NC + i * 8 + q];
            const __half2* h = (const __half2*)&raw;
#pragma unroll
            for (int j = 0; j < 4; ++j) {
                float2 f = __half22float2(h[j]);
                acc[i][2 * j + 0] = f.x;
                acc[i][2 * j + 1] = f.y;
            }
        }
    }
    for (int e = beg + slot; e < end; e += 8) {
        int r = srows[e];
#pragma unroll
        for (int i = 0; i < PL; ++i) {
            float4 raw = S4[r * NC + i * 8 + q];
            const __half2* h = (const __half2*)&raw;
#pragma unroll
            for (int j = 0; j < 4; ++j) {
                float2 f = __half22float2(h[j]);
                acc[i][2 * j + 0] += f.x;
                acc[i][2 * j + 1] += f.y;
            }
        }
    }
#pragma unroll
    for (int d = 8; d < 64; d <<= 1)
#pragma unroll
        for (int i = 0; i < PL; ++i)
#pragma unroll
            for (int j = 0; j < 8; ++j)
                acc[i][j] += __shfl_xor(acc[i][j], d, 64);

    if (lane < 8) {
        float4* D4 = (float4*)DST;   // 8 halfs per float4
#pragma unroll
        for (int i = 0; i < PL; ++i) {
            float4 pk;
            __half2* hp = (__half2*)&pk;
            hp[0] = __floats2half2_rn(di * acc[i][0], di * acc[i][1]);
            hp[1] = __floats2half2_rn(di * acc[i][2], di * acc[i][3]);
            hp[2] = __floats2half2_rn(di * acc[i][4], di * acc[i][5]);
            hp[3] = __floats2half2_rn(di * acc[i][6], di * acc[i][7]);
            D4[node * NC + i * 8 + lane] = pk;
        }
    }
}

// ---------------- GEMM: Y[M,128] = X[M,K](fp16) @ W[K,128] + bias, relu ----------------
// RS: scale rows by rs[] and emit fp16 row-major Y. POOL: instead of writing Y,
// run-length pool rows by (sorted) batch and atomicAdd into gsum[g*128+col].
template<int K, bool RS, bool POOL>
__global__ __launch_bounds__(256) void gemm32(const __half* __restrict__ X,
                                              const float* __restrict__ W,
                                              const float* __restrict__ bias,
                                              const float* __restrict__ rs,
                                              const int* __restrict__ batch,
                                              float* __restrict__ Y, int M) {
    __shared__ float Xt[32][36];
    __shared__ float Wsh[32][128];
    __shared__ int sb[32];
    const int t  = threadIdx.x;
    const int tr = t >> 5;
    const int tc = t & 31;
    const int row0 = blockIdx.x * 32;
    const int rr = t >> 3, kq = t & 7;

    if (POOL && t < 32) sb[t] = (row0 + t < M) ? batch[row0 + t] : -1;

    float acc[4][4];
#pragma unroll
    for (int i = 0; i < 4; ++i)
#pragma unroll
        for (int j = 0; j < 4; ++j) acc[i][j] = 0.f;

    const float2* X2 = (const float2*)X;    // 4 halfs per float2
    const float4* W4 = (const float4*)W;
    float4* Ws4 = (float4*)&Wsh[0][0];

    for (int k0 = 0; k0 < K; k0 += 32) {
        __syncthreads();
        int gr = row0 + rr;
        float2 raw = make_float2(0.f, 0.f);
        if (gr < M) raw = X2[(gr * K + k0 + 4 * kq) >> 2];
        const __half2* hx = (const __half2*)&raw;
        float2 lo = __half22float2(hx[0]);
        float2 hi = __half22float2(hx[1]);
        Xt[4 * kq + 0][rr] = lo.x;
        Xt[4 * kq + 1][rr] = lo.y;
        Xt[4 * kq + 2][rr] = hi.x;
        Xt[4 * kq + 3][rr] = hi.y;
#pragma unroll
        for (int i = t; i < 32 * 32; i += 256)
            Ws4[i] = W4[(k0 + (i >> 5)) * 32 + (i & 31)];
        __syncthreads();
#pragma unroll 4
        for (int k = 0; k < 32; ++k) {
            float4 xf = *reinterpret_cast<const float4*>(&Xt[k][4 * tr]);
            float4 wf = *reinterpret_cast<const float4*>(&Wsh[k][4 * tc]);
            float xv[4] = {xf.x, xf.y, xf.z, xf.w};
            float wv[4] = {wf.x, wf.y, wf.z, wf.w};
#pragma unroll
            for (int i = 0; i < 4; ++i)
#pragma unroll
                for (int j = 0; j < 4; ++j)
                    acc[i][j] = fmaf(xv[i], wv[j], acc[i][j]);
        }
    }
    float4 b = ((const float4*)bias)[tc];

    if (POOL) {
        // pooled epilogue: relu(acc+b) run-length summed by graph -> atomics
        int rung = -1;
        float4 run = make_float4(0.f, 0.f, 0.f, 0.f);
#pragma unroll
        for (int i = 0; i < 4; ++i) {
            int gr = row0 + 4 * tr + i;
            int g = (gr < M) ? sb[4 * tr + i] : -1;
            float4 o = make_float4(fmaxf(acc[i][0] + b.x, 0.f),
                                   fmaxf(acc[i][1] + b.y, 0.f),
                                   fmaxf(acc[i][2] + b.z, 0.f),
                                   fmaxf(acc[i][3] + b.w, 0.f));
            if (g != rung) {
                if (rung >= 0) {
                    float* dst = &Y[rung * 128 + 4 * tc];
                    atomicAdd(dst + 0, run.x);
                    atomicAdd(dst + 1, run.y);
                    atomicAdd(dst + 2, run.z);
                    atomicAdd(dst + 3, run.w);
                }
                run = make_float4(0.f, 0.f, 0.f, 0.f);
                rung = g;
            }
            if (g >= 0) {
                run.x += o.x; run.y += o.y; run.z += o.z; run.w += o.w;
            }
        }
        if (rung >= 0) {
            float* dst = &Y[rung * 128 + 4 * tc];
            atomicAdd(dst + 0, run.x);
            atomicAdd(dst + 1, run.y);
            atomicAdd(dst + 2, run.z);
            atomicAdd(dst + 3, run.w);
        }
        return;
    }

    // normal epilogue: fp16 row-major out (optionally row-scaled)
    __half* Yh = (__half*)Y;
#pragma unroll
    for (int i = 0; i < 4; ++i) {
        int gr = row0 + 4 * tr + i;
        if (gr < M) {
            float4 o = make_float4(fmaxf(acc[i][0] + b.x, 0.f),
                                   fmaxf(acc[i][1] + b.y, 0.f),
                                   fmaxf(acc[i][2] + b.z, 0.f),
                                   fmaxf(acc[i][3] + b.w, 0.f));
            if (RS) {
                float d = rs[gr];
                o.x *= d; o.y *= d; o.z *= d; o.w *= d;
            }
            __half2 h[2];
            h[0] = __floats2half2_rn(o.x, o.y);
            h[1] = __floats2half2_rn(o.z, o.w);
            ((float2*)Yh)[(size_t)gr * 32 + tc] = *(float2*)h;
        }
    }
}

// ---------------- normalize gsum -> mean (counts via binary search) ----------------
__global__ __launch_bounds__(128) void k_div(float* __restrict__ gsum,
                                             const int* __restrict__ batch) {
    int g = blockIdx.x;
    __shared__ float inv;
    if (threadIdx.x == 0) {
        int lo = 0, hi = NN;
        while (lo < hi) { int m = (lo + hi) >> 1; if (batch[m] < g) lo = m + 1; else hi = m; }
        int s = lo;
        lo = 0; hi = NN;
        while (lo < hi) { int m = (lo + hi) >> 1; if (batch[m] < g + 1) lo = m + 1; else hi = m; }
        float c = (float)(lo - s);
        inv = 1.f / fmaxf(c, 1.f);
    }
    __syncthreads();
    gsum[g * 128 + threadIdx.x] *= inv;
}

// ---------------- batched GEMM: {A,B}arr[c][g][t] = GE @ W1-half (128x128 tile) ----------------
__global__ __launch_bounds__(256) void gemm_bat(const float* __restrict__ GE,
                                                const float* __restrict__ W1,
                                                float* __restrict__ Aarr,
                                                float* __restrict__ Barr) {
    __shared__ float Xt[32][132];
    __shared__ float Wsh[32][128];
    const int t  = threadIdx.x;
    const int tr = t >> 4;
    const int tc = t & 15;
    const int row0 = blockIdx.x * 128;
    const int y = blockIdx.y;
    const int z = blockIdx.z;

    const float* Wbase = W1 + (z >> 1) * (HID * HID) + (z & 1) * (128 * HID) + y * 128;

    float acc[8][8];
#pragma unroll
    for (int i = 0; i < 8; ++i)
#pragma unroll
        for (int j = 0; j < 8; ++j) acc[i][j] = 0.f;

    const float4* X4 = (const float4*)GE;

    for (int k0 = 0; k0 < 128; k0 += 32) {
        __syncthreads();
#pragma unroll
        for (int i = 0; i < 4; ++i) {
            int f4 = t + i * 256;
            int row = f4 >> 3, kq = f4 & 7;
            float4 xv = X4[(row0 + row) * 32 + (k0 >> 2) + kq];
            Xt[4 * kq + 0][row] = xv.x;
            Xt[4 * kq + 1][row] = xv.y;
            Xt[4 * kq + 2][row] = xv.z;
            Xt[4 * kq + 3][row] = xv.w;
        }
        const float4* Wc4 = (const float4*)(Wbase + k0 * HID);
#pragma unroll
        for (int i = 0; i < 4; ++i) {
            int f4 = t + i * 256;
            int k = f4 >> 5, c4 = f4 & 31;
            ((float4*)&Wsh[k][0])[c4] = Wc4[k * 64 + c4];
        }
        __syncthreads();
#pragma unroll 2
        for (int k = 0; k < 32; ++k) {
            float xf[8], wf[8];
            *(float4*)&xf[0] = *(const float4*)&Xt[k][8 * tr];
            *(float4*)&xf[4] = *(const float4*)&Xt[k][8 * tr + 4];
            *(float4*)&wf[0] = *(const float4*)&Wsh[k][8 * tc];
            *(float4*)&wf[4] = *(const float4*)&Wsh[k][8 * tc + 4];
#pragma unroll
            for (int i = 0; i < 8; ++i)
#pragma unroll
                for (int j = 0; j < 8; ++j)
                    acc[i][j] = fmaf(xf[i], wf[j], acc[i][j]);
        }
    }
    float* Obase = (z & 1) ? Barr : Aarr;
    float4* O4 = (float4*)Obase;
#pragma unroll
    for (int i = 0; i < 8; ++i) {
        int g = row0 + 8 * tr + i;
        size_t base = ((size_t)((z >> 1) * NG + g) * HID + y * 128 + 8 * tc) >> 2;
        O4[base + 0] = make_float4(acc[i][0], acc[i][1], acc[i][2], acc[i][3]);
        O4[base + 1] = make_float4(acc[i][4], acc[i][5], acc[i][6], acc[i][7]);
    }
}

// ---------------- pair epilogue ----------------
__global__ __launch_bounds__(256) void k_pair(const float* __restrict__ Aarr,
                                              const float* __restrict__ Barr,
                                              const int* __restrict__ ddb,
                                              const int* __restrict__ ecl,
                                              const float* __restrict__ B1,
                                              const float* __restrict__ W2,
                                              const float* __restrict__ B2,
                                              float* __restrict__ out) {
    int p = blockIdx.x * 4 + (threadIdx.x >> 6);
    int lane = threadIdx.x & 63;
    int c = ecl[p];
    int a = ddb[p];
    int b = ddb[NP + p];
    const float4* rA = (const float4*)&Aarr[((size_t)c * NG + a) * HID];
    const float4* rB = (const float4*)&Barr[((size_t)c * NG + b) * HID];
    const float4* b1 = (const float4*)&B1[c * HID];
    const float4* w2 = (const float4*)&W2[c * HID];
    float4 va = rA[lane], vb = rB[lane], v1 = b1[lane], v2 = w2[lane];
    float hx = va.x + vb.x + v1.x;
    float hy = va.y + vb.y + v1.y;
    float hz = va.z + vb.z + v1.z;
    float hw = va.w + vb.w + v1.w;
    float s = 0.f;
    s = fmaf(hx > 0.f ? hx : 0.f, v2.x, s);
    s = fmaf(hy > 0.f ? hy : 0.f, v2.y, s);
    s = fmaf(hz > 0.f ? hz : 0.f, v2.z, s);
    s = fmaf(hw > 0.f ? hw : 0.f, v2.w, s);
    for (int o = 32; o; o >>= 1) s += __shfl_down(s, o, 64);
    if (lane == 0) out[p] = s + B2[c];
}

// ---------------- launch ----------------
extern "C" void kernel_launch(void* const* d_in, const int* in_sizes, int n_in,
                              void* d_out, int out_size, void* d_ws, size_t ws_size,
                              hipStream_t stream) {
    const float* x    = (const float*)d_in[0];
    const float* c1w  = (const float*)d_in[1];
    const float* c1b  = (const float*)d_in[2];
    const float* c2w  = (const float*)d_in[3];
    const float* c2b  = (const float*)d_in[4];
    const float* rw1  = (const float*)d_in[5];
    const float* rb1  = (const float*)d_in[6];
    const float* rw2  = (const float*)d_in[7];
    const float* rb2  = (const float*)d_in[8];
    const int*   eidx = (const int*)d_in[9];    // [2, NE]: rows then cols
    const int*   batch= (const int*)d_in[10];
    const int*   ddb  = (const int*)d_in[11];   // [2, NP]
    const int*   ecl  = (const int*)d_in[12];
    float* out = (float*)d_out;

    // ---- workspace layout (floats) ----
    // off(50048) | srows(NE) | dinv(50048) | bufA(6.4M) | bufB(6.4M)
    // temporal aliases:
    //   ebuf  (int NE)         -> bufA[0..0.8M)      (k_part .. k_bsort)
    //   cnt/btot/bbase         -> bufB[1.7M..1.86M)  (k_cnt .. k_bsort)
    //   xs    (fp16 [NN][64])  -> bufB[0..1.6M)      (k_bsort .. gath1)
    //   aggXh (fp16 [NN][64])  -> bufA[0..1.6M)      (gath1 .. gemm1)
    //   H1h   (fp16 [NN][128]) -> bufB[0..3.2M)      (gemm1 .. gath2)
    //   aggHh (fp16 [NN][128]) -> bufA[0..3.2M)      (gath2 .. gemm2)
    //   gsum  (f32 131072)     -> bufA[4.5M..4.63M)  (zeroed in gath1; gemm2 .. gemm_bat)
    //   Aarr  (f32 4.19M)      -> bufA[0..4.19M)     (gemm_bat .. k_pair)
    //   Barr  (f32 4.19M)      -> bufB[0..4.19M)     (gemm_bat .. k_pair)
    int*   off   = (int*)d_ws;
    int*   srows = off + 50048;
    float* dinv  = (float*)(srows + NE);
    float* bufA  = dinv + 50048;
    float* bufB  = bufA + NN * EMB;

    int*    ebuf  = (int*)bufA;
    int*    cnt   = (int*)(bufB + 1700000);
    int*    btot  = cnt + NB * NCHUNK;
    int*    bbase = btot + 512;
    __half* xs    = (__half*)bufB;
    __half* aggXh = (__half*)bufA;
    __half* H1h   = (__half*)bufB;
    __half* aggHh = (__half*)bufA;
    float*  gsum  = bufA + 4500000;
    float*  Aarr  = bufA;
    float*  Barr  = bufB;

    const int* erow = eidx;
    const int* ecol = eidx + NE;

    // ---- CSR build (bucketed, LDS-atomic only) + fused x->fp16 prescale ----
    k_cnt  <<<NCHUNK, 256, 0, stream>>>(ecol, cnt);
    k_bscan<<<NB,     512, 0, stream>>>(cnt, btot);
    k_btot <<<1,      512, 0, stream>>>(btot, bbase);
    k_part <<<NCHUNK, 256, 0, stream>>>(erow, ecol, cnt, bbase, ebuf);
    k_bsort<<<NB,     256, 0, stream>>>(ebuf, bbase, x, off, dinv, srows, xs);

    // ---- layer 1: aggX(fp16) = gather(xs) [+ zero gsum] ; H1'(fp16) = dinv*relu(aggX@W1+b1) ----
    k_gath_h<INCH,true><<<CDIV(NN,4),256,0,stream>>>(off, srows, dinv, xs, aggXh, gsum);
    gemm32<INCH,true,false><<<CDIV(NN,32),256,0,stream>>>(aggXh, c1w, c1b, dinv, nullptr, (float*)H1h, NN);

    // ---- layer 2: aggH(fp16) = gather(H1') ; gemm2 + fused mean-pool atomics ----
    k_gath_h<EMB,false><<<CDIV(NN,4),256,0,stream>>>(off, srows, dinv, H1h, aggHh, nullptr);
    gemm32<EMB,false,true><<<CDIV(NN,32),256,0,stream>>>(aggHh, c2w, c2b, nullptr, batch, gsum, NN);
    k_div<<<NG,128,0,stream>>>(gsum, batch);

    // ---- regressor: {A,B} = GE @ W1 halves for all 16 lines, then pair epilogue ----
    dim3 bgrid(NG/128, 2, 2*NCL);
    gemm_bat<<<bgrid,256,0,stream>>>(gsum, rw1, Aarr, Barr);
    k_pair<<<NP/4,256,0,stream>>>(Aarr, Barr, ddb, ecl, rb1, rw2, rb2, out);
}